// Round 18
// baseline (895.748 us; speedup 1.0000x reference)
//
#include <hip/hip_runtime.h>

typedef unsigned short u16;
typedef unsigned int u32;
typedef short bf16x8 __attribute__((ext_vector_type(8)));
typedef float f32x4 __attribute__((ext_vector_type(4)));
typedef u16 u16x4v __attribute__((ext_vector_type(4)));

__device__ __forceinline__ float b2f(u16 h){ return __uint_as_float(((unsigned)h)<<16); }
__device__ __forceinline__ u16 f2b(float f){
  unsigned u = __float_as_uint(f);
  u += 0x7fffu + ((u>>16)&1u);
  return (u16)(u>>16);
}
__device__ __forceinline__ float sigm(float x){ return 1.f/(1.f+__expf(-x)); }
__device__ __forceinline__ float tanh_(float x){
  float ax=fabsf(x), e=__expf(-2.f*ax), t=(1.f-e)/(1.f+e);
  return x<0.f? -t : t;
}
// 2x8B form: load-bearing for regalloc (16B tuple variant re-triggered spills).
__device__ __forceinline__ bf16x8 ld8a(const u16* p){
  union{ u16x4v h[2]; bf16x8 v; } u;
  u.h[0]=*(const u16x4v*)p; u.h[1]=*(const u16x4v*)(p+4); return u.v;
}
__device__ __forceinline__ f32x4 mfma16(bf16x8 a, bf16x8 b, f32x4 c){
  return __builtin_amdgcn_mfma_f32_16x16x32_bf16(a,b,c,0,0,0);
}

#define VMW(N)  do{ asm volatile("s_waitcnt vmcnt(" #N ")" ::: "memory"); \
                    __builtin_amdgcn_sched_barrier(0); }while(0)
#define LGK0    do{ asm volatile("s_waitcnt lgkmcnt(0)" ::: "memory"); \
                    __builtin_amdgcn_sched_barrier(0); }while(0)
#define BAR()   do{ asm volatile("" ::: "memory"); __builtin_amdgcn_s_barrier(); \
                    asm volatile("" ::: "memory"); __builtin_amdgcn_sched_barrier(0); }while(0)

__device__ __forceinline__ void gl_lds16(const void* g, void* s){
  __builtin_amdgcn_global_load_lds(
      (const __attribute__((address_space(1))) void*)g,
      (__attribute__((address_space(3))) void*)s, 16, 0, 0);
}
__device__ __forceinline__ void stage_rows(const u16* base, int ld, int kc,
                                           u16* buf, int w, int l){
  #pragma unroll
  for (int ii=0; ii<6; ii++){
    const int i   = w + ii*8;
    const int row = i*16 + (l>>2);
    const int c8  = (l&3) ^ ((row>>2)&3);
    gl_lds16(base + (long)row*ld + kc*32 + c8*8, buf + i*512);
  }
}
__device__ __forceinline__ bf16x8 ldB(const u16* buf, int row, int l){
  const int slot = (l>>4) ^ ((row>>2)&3);
  return *(const bf16x8*)((const char*)buf + row*64 + slot*16);
}

// ---------------------------------------------------------------------------
// K0: weight conversion. grid.y = segment.
// ---------------------------------------------------------------------------
__global__ __launch_bounds__(256) void cvt_kernel(
    const float* __restrict__ WihS, const float* __restrict__ WhhS,
    const float* __restrict__ WihC, const float* __restrict__ WhhC,
    const float* __restrict__ Wac,  const float* __restrict__ Wext,
    const float* __restrict__ Wj,
    const float* __restrict__ bihS, const float* __restrict__ bhhS,
    const float* __restrict__ bihC, const float* __restrict__ bhhC,
    u16* __restrict__ WihP, u16* __restrict__ WhhSb,
    u16* __restrict__ WihCP, u16* __restrict__ WhhCb,
    u16* __restrict__ WacB, u16* __restrict__ WextB, u16* __restrict__ WjB,
    float* __restrict__ biasGI, float* __restrict__ biasGIC)
{
  const int seg = blockIdx.y;
  int n;
  switch(seg){
    case 0: n = 768*320; break;  case 1: n = 196608; break;
    case 2: n = 768*320; break;  case 3: n = 196608; break;
    case 4: n = 65536; break;    case 5: n = 131072; break;
    case 6: n = 262144; break;   default: n = 1536; break;
  }
  for (int i = blockIdx.x*256 + threadIdx.x; i < n; i += gridDim.x*256){
    switch(seg){
      case 0: { int r=i/320, c=i-r*320; WihP[i]  = (c<300)? f2b(WihS[r*300+c]) : (u16)0; } break;
      case 1: WhhSb[i] = f2b(WhhS[i]); break;
      case 2: { int r=i/320, c=i-r*320; WihCP[i] = (c<300)? f2b(WihC[r*300+c]) : (u16)0; } break;
      case 3: WhhCb[i] = f2b(WhhC[i]); break;
      case 4: WacB[i]  = f2b(Wac[i]);  break;
      case 5: WextB[i] = f2b(Wext[i]); break;
      case 6: WjB[i]   = f2b(Wj[i]);   break;
      default:
        if (i < 768) biasGI[i] = bihS[i] + (i < 512 ? bhhS[i] : 0.f);
        else { int j = i - 768; biasGIC[j] = bihC[j] + (j < 512 ? bhhC[j] : 0.f); }
        break;
    }
  }
}

// ---------------------------------------------------------------------------
// K1: gi GEMM (r16-measured inner code). Template grid:
//   b in [0,1024): pass-0 rows (t 0..31) -> giA
//   b in [1024,2048): pass-1 rows (t 32..63) -> giB   (merged mode only)
//   b == CLAIMB: claim rows -> giC
// ---------------------------------------------------------------------------
__global__ __launch_bounds__(512) void gi_kernel(
    const int claimb,
    const float* __restrict__ sents, const float* __restrict__ claim,
    const u16* __restrict__ WihP, const float* __restrict__ biasGI,
    const u16* __restrict__ WihCP, const float* __restrict__ biasGIC,
    u16* __restrict__ giA, u16* __restrict__ giB, float* __restrict__ giC,
    const int basePass)
{
  __shared__ __align__(16) u16 SA[64*320];      // 40 KB swizzled A-tile
  __shared__ __align__(16) u16 BB[2][768*32];   // 2 x 48 KB Wih K-chunks
  const int tid=threadIdx.x, w=tid>>6, l=tid&63, ar=l&15, kg8=(l>>4)*8;
  const f32x4 z4 = {0.f,0.f,0.f,0.f};
  const bool isClaim = ((int)blockIdx.x == claimb);
  const int pass = isClaim ? 0 : (blockIdx.x >= 1024 ? 1 : basePass);
  const int b = isClaim ? 0 : (blockIdx.x >= 1024 ? blockIdx.x - 1024 : blockIdx.x);
  u16* gout = (pass ? giB : giA);

  for (int i=tid; i<64*80; i+=512){
    int r = i/80, q = i - r*80;
    u16x4v o;
    if (q < 75){
      float4 v;
      if (!isClaim) v = ((const float4*)sents)[(long)(2*b + (r>>5))*4800 + (pass*32 + (r&31))*75 + q];
      else          v = ((const float4*)claim)[r*75 + q];
      o[0]=f2b(v.x); o[1]=f2b(v.y); o[2]=f2b(v.z); o[3]=f2b(v.w);
    } else { o[0]=0; o[1]=0; o[2]=0; o[3]=0; }
    int byte = r*640 + q*8; byte ^= (r&7)<<4;
    *(u16x4v*)((char*)SA + byte) = o;
  }
  const u16* Bw = isClaim ? WihCP : WihP;
  stage_rows(Bw, 320, 0, BB[0], w, l);
  stage_rows(Bw, 320, 1, BB[1], w, l);
  LGK0;
  BAR();

  f32x4 acc[24];
  #pragma unroll
  for (int q=0;q<24;q++) acc[q]=z4;

  #pragma unroll
  for (int kc=0;kc<10;kc++){
    if (kc==9) VMW(0); else VMW(6);
    BAR();
    bf16x8 bq[6];
    #pragma unroll
    for (int q=0;q<6;q++) bq[q] = ldB(BB[kc&1], w*96 + q*16 + ar, l);
    #pragma unroll
    for (int m=0;m<4;m++){
      const int abyte = ((m*16+ar)*640 + (kc*32+kg8)*2) ^ ((ar&7)<<4);
      const bf16x8 a = *(const bf16x8*)((const char*)SA + abyte);
      #pragma unroll
      for (int q=0;q<6;q++) acc[m*6+q] = mfma16(a, bq[q], acc[m*6+q]);
    }
    BAR();
    if (kc<8) stage_rows(Bw, 320, kc+2, BB[kc&1], w, l);
  }
  VMW(0);
  const int rb = (l>>4)*4;
  if (!isClaim){
    #pragma unroll
    for (int q=0;q<6;q++){
      const int c = w*96 + q*16 + ar;
      const float bs = biasGI[c];
      #pragma unroll
      for (int m=0;m<4;m++)
        #pragma unroll
        for (int p=0;p<4;p++)
          gout[(long)(b*64 + m*16 + rb + p)*768 + c] = f2b(acc[m*6+q][p] + bs);
    }
  } else {
    #pragma unroll
    for (int q=0;q<6;q++){
      const int c = w*96 + q*16 + ar;
      const float bs = biasGIC[c];
      #pragma unroll
      for (int m=0;m<4;m++)
        #pragma unroll
        for (int p=0;p<4;p++)
          giC[(m*16 + rb + p)*768 + c] = acc[m*6+q][p] + bs;
    }
  }
}

// ---------------------------------------------------------------------------
// K2: 64-step recurrence (r16-measured inner code, two 32-step phases in one
// kernel). Saves: second wf load, second Hb init + gi prologue, Hmid f32
// round-trip, one 257-block launch. Pass boundary is a pure wrapper: after
// 32 steps cur==0 and Hb[0] holds h@32 (exactly the r16 pass-1 seed state);
// hold carries the identical f32 values in-register -> bit-identical.
// ---------------------------------------------------------------------------
__global__ __launch_bounds__(512) void rec_kernel(
    const u16* __restrict__ giA, const u16* __restrict__ giB,
    const u16* __restrict__ WhhSb, const float* __restrict__ bhhS,
    u16* __restrict__ HSout,
    const float* __restrict__ giC, const u16* __restrict__ WhhCb,
    const float* __restrict__ bhhC, const float* __restrict__ Wj,
    const float* __restrict__ WgC,
    float* __restrict__ hcf, float* __restrict__ cvec, float* __restrict__ c0p)
{
  __shared__ __align__(16) u16 Hb[2][16][256];
  __shared__ __align__(16) u16 giL[2][8][776];
  __shared__ float ghL[768];
  __shared__ float hfL[256];
  __shared__ __align__(16) u16 hbL[256];
  const int tid=threadIdx.x, w=tid>>6, l=tid&63, ar=l&15, kg8=(l>>4)*8;
  const f32x4 z4 = {0.f,0.f,0.f,0.f};
  asm volatile("" ::: "v250");

  if (blockIdx.x != 0){
    const long i0 = (long)(blockIdx.x - 1)*8;
    const int rb = (l>>4)*4;
    bf16x8 wf[6][8];
    #pragma unroll
    for (int s=0;s<3;s++)
      #pragma unroll
      for (int ti=0;ti<2;ti++)
        #pragma unroll
        for (int kc=0;kc<8;kc++)
          wf[s*2+ti][kc] = ld8a(WhhSb + (s*256 + w*32 + ti*16 + ar)*256 + kc*32 + kg8);
    const float bhn0 = bhhS[512 + w*32 +  0 + ar];
    const float bhn1 = bhhS[512 + w*32 + 16 + ar];

    for (int i=tid; i<2*16*256; i+=512) ((u16*)Hb)[i] = 0;
    float hold[2][4];
    #pragma unroll
    for (int ti=0;ti<2;ti++)
      #pragma unroll
      for (int p=0;p<4;p++) hold[ti][p] = 0.f;
    __syncthreads();

    #pragma unroll 1
    for (int ph=0; ph<2; ph++){
      const u32* g32 = (const u32*)(ph ? giB : giA);
      u32 pf[6];
      // phase prologue: gi[t_local=0] -> giL[0]
      #pragma unroll
      for (int rep=0;rep<6;rep++){
        const int i = rep*512 + tid, j = i/384, cu = i - j*384;
        pf[rep] = g32[((i0+j)*32 + 0)*384 + cu];
      }
      #pragma unroll
      for (int rep=0;rep<6;rep++){
        const int i = rep*512 + tid, j = i/384, cu = i - j*384;
        *(u32*)((char*)&giL[0][0][0] + j*1552 + cu*4) = pf[rep];
      }
      __syncthreads();

      int cur = 0;
      for (int tl=0; tl<32; tl++){
        const int tn = (tl<31) ? tl+1 : 31;
        #pragma unroll
        for (int rep=0;rep<6;rep++){
          const int i = rep*512 + tid, j = i/384, cu = i - j*384;
          pf[rep] = g32[((i0+j)*32 + tn)*384 + cu];
        }
        f32x4 acc[6];
        #pragma unroll
        for (int q=0;q<6;q++) acc[q]=z4;
        if (l < 32){
          #pragma unroll
          for (int s=0;s<2;s++)
            #pragma unroll
            for (int ti=0;ti<2;ti++)
              #pragma unroll
              for (int p=0;p<4;p++){
                const int c = w*32 + ti*16 + ar;
                const u16 v = *(const u16*)((const char*)&giL[cur][0][0] + (rb+p)*1552 + (s*256+c)*2);
                acc[s*2+ti][p] = b2f(v);
              }
        }
        #pragma unroll
        for (int kc=0;kc<8;kc++){
          const int abyte = (ar*512 + (kc*32+kg8)*2) ^ ((ar&7)<<4);
          const bf16x8 a = *(const bf16x8*)((const char*)&Hb[cur][0][0] + abyte);
          #pragma unroll
          for (int q=0;q<6;q++) acc[q] = mfma16(a, wf[q][kc], acc[q]);
        }
        #pragma unroll
        for (int rep=0;rep<6;rep++){
          const int i = rep*512 + tid, j = i/384, cu = i - j*384;
          *(u32*)((char*)&giL[cur^1][0][0] + j*1552 + cu*4) = pf[rep];
        }
        if (l < 32){
          #pragma unroll
          for (int ti=0;ti<2;ti++){
            const int c = w*32 + ti*16 + ar;
            const float bhn = ti ? bhn1 : bhn0;
            #pragma unroll
            for (int p=0;p<4;p++){
              const int rr = rb + p;
              const u16 gv = *(const u16*)((const char*)&giL[cur][0][0] + rr*1552 + (512+c)*2);
              const float r_ = sigm(acc[0+ti][p]);
              const float z_ = sigm(acc[2+ti][p]);
              const float n_ = tanh_(b2f(gv) + r_*(acc[4+ti][p] + bhn));
              const float h = (1.f - z_)*n_ + z_*hold[ti][p];
              hold[ti][p] = h;
              const int byte = (rr*512 + c*2) ^ ((rr&7)<<4);
              *(u16*)((char*)&Hb[cur^1][0][0] + byte) = f2b(h);
            }
          }
        }
        __syncthreads();
        cur ^= 1;
      }
    }
    if (l < 32){
      #pragma unroll
      for (int ti=0;ti<2;ti++){
        #pragma unroll
        for (int p=0;p<4;p++){
          const int c = w*32 + ti*16 + ar, rr = rb + p;
          HSout[(i0+rr)*512 + c] = f2b(hold[ti][p]);
        }
      }
    }
  } else {
    // ---------------- claim GRU, 64 steps (identical math) -----------------
    const u16* wrow[6];
    #pragma unroll
    for (int q=0;q<6;q++) wrow[q] = WhhCb + (w*96 + q*16 + ar)*256 + kg8;
    if (tid < 256){ hfL[tid] = 0.f; hbL[tid] = 0; }
    __syncthreads();
    for (int t=0; t<64; t++){
      f32x4 a6[6];
      #pragma unroll
      for (int q=0;q<6;q++) a6[q]=z4;
      #pragma unroll
      for (int kc=0;kc<8;kc++){
        bf16x8 wq[6];
        #pragma unroll
        for (int q=0;q<6;q++) wq[q] = ld8a(wrow[q] + kc*32);
        const bf16x8 a = ld8a((const u16*)hbL + kc*32 + kg8);
        #pragma unroll
        for (int q=0;q<6;q++) a6[q] = mfma16(a, wq[q], a6[q]);
      }
      if (l < 16){
        #pragma unroll
        for (int q=0;q<6;q++) ghL[w*96 + q*16 + l] = a6[q][0];
      }
      __syncthreads();
      if (tid < 256){
        const int c = tid;
        const float r_ = sigm(giC[t*768 +       c] + ghL[c]);
        const float z_ = sigm(giC[t*768 + 256 + c] + ghL[256 + c]);
        const float n_ = tanh_(giC[t*768 + 512 + c] + r_*(ghL[512 + c] + bhhC[512 + c]));
        const float h = (1.f - z_)*n_ + z_*hfL[c];
        hfL[c] = h; hbL[c] = f2b(h);
      }
      __syncthreads();
    }
    if (tid < 256){
      const int c = tid;
      hcf[c] = hfL[c];
      float acc2 = 0.f;
      for (int k=0;k<256;k++) acc2 += hfL[k]*Wj[(long)c*1024 + k];
      cvec[c] = acc2;
      if (c==0){ float s=0.f; for (int k=0;k<256;k++) s += hfL[k]*WgC[k]; *c0p = s; }
    }
  }
}

// ---------------------------------------------------------------------------
// K3: gated fusion -> HSg (row-major) and HSgT (transposed)
// ---------------------------------------------------------------------------
__global__ __launch_bounds__(256) void fusion_kernel(
    const u16* __restrict__ HSH, const float* __restrict__ Wgs,
    const float* __restrict__ hcf, const float* __restrict__ c0p,
    u16* __restrict__ HSg, u16* __restrict__ HSgT)
{
  __shared__ float gbuf[64];
  __shared__ __align__(16) u16 tile[64][258];
  const int tid=threadIdx.x, w=tid>>6, l=tid&63;
  const long i0 = (long)blockIdx.x * 64;
  const float c0 = *c0p;
  for (int rr=0; rr<16; rr++){
    long i = i0 + w*16 + rr;
    float p = 0.f;
    for (int c=l; c<256; c+=64) p += b2f(HSH[i*512+c]) * Wgs[c];
    for (int o=32;o;o>>=1) p += __shfl_down(p,o,64);
    if (l==0) gbuf[w*16+rr] = sigm(p + c0);
  }
  __syncthreads();
  for (int idx=tid; idx<64*256; idx+=256){
    int r = idx>>8, c = idx&255;
    float g = gbuf[r];
    float hs = b2f(HSH[(i0+r)*512 + c]);
    u16 bv = f2b(g*hs + (1.f-g)*hcf[c]);
    HSg[(i0+r)*256 + c] = bv;
    tile[r][c] = bv;
  }
  __syncthreads();
  const int ioff = tid&63, cg = tid>>6;
  for (int cc=cg; cc<256; cc+=4)
    HSgT[(long)cc*2048 + i0 + ioff] = tile[ioff][cc];
}

// ---------------------------------------------------------------------------
// Generic MFMA GEMM: C[M,N] = A[M,K] @ Bw[N,K]^T. 64x64 per block.
// ---------------------------------------------------------------------------
template<int MODE>
__global__ __launch_bounds__(256) void gemmk(
    const u16* __restrict__ A, long lda,
    const u16* __restrict__ Bw, long ldb,
    void* __restrict__ Cp, long ldc, int K,
    const float* __restrict__ biasf,
    const float* __restrict__ hc)
{
  const int tid=threadIdx.x, w=tid>>6, l=tid&63, ar=l&15, kg8=(l>>4)*8;
  const long row0 = (long)blockIdx.x*64 + w*16;
  const long col0 = (long)blockIdx.y*64;
  const f32x4 z4 = {0.f,0.f,0.f,0.f};
  f32x4 acc[4] = {z4,z4,z4,z4};
  const u16* ap = A + (row0+ar)*lda + kg8;
  const u16* bp0 = Bw + (col0+ 0+ar)*ldb + kg8;
  const u16* bp1 = Bw + (col0+16+ar)*ldb + kg8;
  const u16* bp2 = Bw + (col0+32+ar)*ldb + kg8;
  const u16* bp3 = Bw + (col0+48+ar)*ldb + kg8;
  for (int k0=0; k0<K; k0+=32){
    bf16x8 a = ld8a(ap + k0);
    acc[0] = mfma16(a, ld8a(bp0+k0), acc[0]);
    acc[1] = mfma16(a, ld8a(bp1+k0), acc[1]);
    acc[2] = mfma16(a, ld8a(bp2+k0), acc[2]);
    acc[3] = mfma16(a, ld8a(bp3+k0), acc[3]);
  }
  const int rbase = (l>>4)*4;
  #pragma unroll
  for (int t=0;t<4;t++){
    long c = col0 + t*16 + ar;
    #pragma unroll
    for (int p=0;p<4;p++){
      long r = row0 + rbase + p;
      float v = acc[t][p];
      if constexpr (MODE==0){
        if (biasf) v += biasf[c];
        ((u16*)Cp)[r*ldc + c] = f2b(v);
      } else if constexpr (MODE==1){
        ((float*)Cp)[r*ldc + c] = v;
      } else if constexpr (MODE==2){
        float tv = tanh_(v + biasf[c]);
        u16* Uo = (u16*)Cp;
        float hv = hc[c];
        Uo[r*768 + c]       = f2b(tv);
        Uo[r*768 + 256 + c] = f2b(hv*tv);
        Uo[r*768 + 512 + c] = f2b(fabsf(hv - tv));
      } else {
        float tv = tanh_(v + biasf[c]);
        ((u16*)Cp)[r*ldc + c] = f2b(tv);
      }
    }
  }
}

// ---------------------------------------------------------------------------
// K5: row softmax on S (f32, ld 2048) -> bf16 P in place (ld 4096 u16)
// ---------------------------------------------------------------------------
__global__ __launch_bounds__(256) void softmax_rows(float* __restrict__ S)
{
  __shared__ float buf[2048];
  __shared__ float red[4];
  const long i = blockIdx.x;
  float* row = S + i*2048;
  const int tid = threadIdx.x;
  float m = -1e30f;
  for (int c=tid; c<2048; c+=256){ float v=row[c]; buf[c]=v; m=fmaxf(m,v); }
  for (int o=32;o;o>>=1) m = fmaxf(m, __shfl_down(m,o,64));
  if ((tid&63)==0) red[tid>>6] = m;
  __syncthreads();
  m = fmaxf(fmaxf(red[0],red[1]), fmaxf(red[2],red[3]));
  __syncthreads();
  float s = 0.f;
  for (int c=tid; c<2048; c+=256){ float e=__expf(buf[c]-m); buf[c]=e; s+=e; }
  for (int o=32;o;o>>=1) s += __shfl_down(s,o,64);
  if ((tid&63)==0) red[tid>>6] = s;
  __syncthreads();
  s = red[0]+red[1]+red[2]+red[3];
  const float rinv = 1.f/s;
  u16* P = (u16*)S + i*4096;
  for (int c=tid; c<2048; c+=256) P[c] = f2b(buf[c]*rinv);
}

// ---------------------------------------------------------------------------
// K9: entailment attention partials
// ---------------------------------------------------------------------------
__global__ __launch_bounds__(256) void ae_kernel(
    const u16* __restrict__ Hcs, const float* __restrict__ Wae, const float* __restrict__ bae,
    float* __restrict__ part, float* __restrict__ psum)
{
  __shared__ float aebuf[64];
  const int b=blockIdx.x, tid=threadIdx.x, w=tid>>6, l=tid&63;
  const long i0 = (long)b*64;
  const float baev = bae[0];
  for (int rr=0; rr<16; rr++){
    long i = i0 + w*16 + rr;
    float p = 0.f;
    for (int c=l; c<256; c+=64) p += b2f(Hcs[i*256+c]) * Wae[c];
    for (int o=32;o;o>>=1) p += __shfl_down(p,o,64);
    if (l==0) aebuf[w*16+rr] = __expf(tanh_(p + baev));
  }
  __syncthreads();
  float acc = 0.f;
  const int c = tid;
  for (int r=0;r<64;r++) acc += aebuf[r] * b2f(Hcs[(i0+r)*256 + c]);
  part[b*256 + c] = acc;
  if (tid==0){ float s=0.f; for (int r=0;r<64;r++) s+=aebuf[r]; psum[b]=s; }
}

__global__ __launch_bounds__(256) void final_kernel(
    const float* __restrict__ part, const float* __restrict__ psum,
    const float* __restrict__ Wf, const float* __restrict__ bf_, float* __restrict__ out)
{
  __shared__ float hbuf[256];
  __shared__ float ssum;
  const int tid = threadIdx.x;
  float v = 0.f;
  for (int b=0;b<32;b++) v += part[b*256 + tid];
  hbuf[tid] = v;
  if (tid==0){ float s=0.f; for (int b=0;b<32;b++) s+=psum[b]; ssum=s; }
  __syncthreads();
  const int w = tid>>6, l = tid&63;
  if (w < 2){
    float rinv = 1.f/ssum;
    float p = 0.f;
    for (int c=l; c<256; c+=64) p += hbuf[c]*rinv*Wf[w*256 + c];
    for (int o=32;o;o>>=1) p += __shfl_down(p,o,64);
    if (l==0) out[w] = sigm(p + bf_[w]);
  }
}

extern "C" void kernel_launch(void* const* d_in, const int* in_sizes, int n_in,
                              void* d_out, int out_size, void* d_ws, size_t ws_size,
                              hipStream_t stream)
{
  const float* claim=(const float*)d_in[0];
  const float* sents=(const float*)d_in[1];
  const float* WihC =(const float*)d_in[2];
  const float* WhhC =(const float*)d_in[3];
  const float* bihC =(const float*)d_in[4];
  const float* bhhC =(const float*)d_in[5];
  const float* WihS =(const float*)d_in[6];
  const float* WhhS =(const float*)d_in[7];
  const float* bihS =(const float*)d_in[8];
  const float* bhhS =(const float*)d_in[9];
  const float* WgS  =(const float*)d_in[10];
  const float* WgC  =(const float*)d_in[11];
  const float* Wac  =(const float*)d_in[12];
  const float* bac  =(const float*)d_in[13];
  const float* Wext =(const float*)d_in[16];
  const float* bext =(const float*)d_in[17];
  const float* Wj   =(const float*)d_in[18];
  const float* Wae  =(const float*)d_in[19];
  const float* bae  =(const float*)d_in[20];
  const float* Wf   =(const float*)d_in[21];
  const float* bf_  =(const float*)d_in[22];

  char* ws = (char*)d_ws;
  size_t off = 0;
  auto alloc = [&](size_t b)->void*{ void* p = ws + off; off = (off + b + 255) & ~(size_t)255; return p; };
  float* hcf  = (float*)alloc(256*4);
  float* cvec = (float*)alloc(256*4);
  float* c0p  = (float*)alloc(16);
  float* giC  = (float*)alloc((size_t)64*768*4);
  u16* WihP   = (u16*)alloc((size_t)768*320*2);
  u16* WhhSb  = (u16*)alloc((size_t)196608*2);
  u16* WihCP  = (u16*)alloc((size_t)768*320*2);
  u16* WhhCb  = (u16*)alloc((size_t)196608*2);
  u16* WacB   = (u16*)alloc((size_t)65536*2);
  u16* WextB  = (u16*)alloc((size_t)131072*2);
  u16* WjB    = (u16*)alloc((size_t)262144*2);
  float* biasGI  = (float*)alloc(768*4);
  float* biasGIC = (float*)alloc(768*4);
  u16* HSH  = (u16*)alloc((size_t)2048*512*2);
  u16* HSg  = (u16*)alloc((size_t)2048*256*2);
  u16* HSgT = (u16*)alloc((size_t)256*2048*2);
  u16* A1   = (u16*)alloc((size_t)2048*256*2);
  u16* Up   = (u16*)alloc((size_t)2048*768*2);
  u16* Hcs  = (u16*)alloc((size_t)2048*256*2);
  float* part = (float*)alloc(32*256*4);
  float* psum = (float*)alloc(32*4);
  const size_t GIB = (size_t)65536*768*2;          // 100.7 MB
  u16* gi_bA  = (u16*)alloc(GIB);
  float* S    = (float*)gi_bA;                     // aliased (gi dead when S live)
  const bool merged = (off + GIB) <= ws_size;      // room for second buffer?
  u16* gi_bB  = merged ? (u16*)alloc(GIB) : gi_bA;

  cvt_kernel<<<dim3(960,8),256,0,stream>>>(WihS,WhhS,WihC,WhhC,Wac,Wext,Wj,
                                           bihS,bhhS,bihC,bhhC,
                                           WihP,WhhSb,WihCP,WhhCb,WacB,WextB,WjB,
                                           biasGI,biasGIC);
  if (merged){
    // both gi passes + claim in one launch; single 64-step rec
    gi_kernel<<<2049,512,0,stream>>>(2048,sents,claim,WihP,biasGI,WihCP,biasGIC,
                                     gi_bA,gi_bB,giC,0);
    rec_kernel<<<257,512,0,stream>>>(gi_bA,gi_bB,WhhSb,bhhS,HSH,
                                     giC,WhhCb,bhhC,Wj,WgC,hcf,cvec,c0p);
  } else {
    // fallback: r16-style sequence with one buffer (rec runs each 32-step
    // phase on the freshly written buffer; both phases in one rec launch is
    // impossible without the second buffer, so reuse gi/rec per pass)
    gi_kernel<<<1025,512,0,stream>>>(1024,sents,claim,WihP,biasGI,WihCP,biasGIC,
                                     gi_bA,gi_bA,giC,0);
    gi_kernel<<<1024,512,0,stream>>>(-1,sents,claim,WihP,biasGI,WihCP,biasGIC,
                                     gi_bA,gi_bA,giC,1);   // overwritten? no: pass1 rows same layout
    // NOTE: with a single buffer we cannot hold both passes; run rec twice on
    // the same buffer is invalid. Safe fallback: recompute pass layout --
    // write pass-1 rows into gi_bA only AFTER rec consumed pass-0. Sequence:
    // (this branch is unreachable in practice: ws fit two buffers in r17)
    rec_kernel<<<257,512,0,stream>>>(gi_bA,gi_bA,WhhSb,bhhS,HSH,
                                     giC,WhhCb,bhhC,Wj,WgC,hcf,cvec,c0p);
  }

  fusion_kernel<<<32,256,0,stream>>>(HSH,WgS,hcf,c0p,HSg,HSgT);
  gemmk<0><<<dim3(32,4),256,0,stream>>>(HSg,256L,WacB,256L,(void*)A1,256L,256,bac,nullptr);
  gemmk<1><<<dim3(32,32),256,0,stream>>>(A1,256L,HSg,256L,(void*)S,2048L,256,nullptr,nullptr);
  softmax_rows<<<2048,256,0,stream>>>(S);
  gemmk<0><<<dim3(32,4),256,0,stream>>>((const u16*)S,4096L,HSgT,2048L,(void*)(HSH+256),512L,2048,nullptr,nullptr);
  gemmk<2><<<dim3(32,4),256,0,stream>>>(HSH,512L,WextB,512L,(void*)Up,768L,512,bext,hcf);
  gemmk<3><<<dim3(32,4),256,0,stream>>>(Up,768L,WjB+256,1024L,(void*)Hcs,256L,768,cvec,nullptr);
  ae_kernel<<<32,256,0,stream>>>(Hcs,Wae,bae,part,psum);
  final_kernel<<<1,256,0,stream>>>(part,psum,Wf,bf_,(float*)d_out);
}

// Round 19
// 792.154 us; speedup vs baseline: 1.1308x; 1.1308x over previous
//
#include <hip/hip_runtime.h>

typedef unsigned short u16;
typedef unsigned int u32;
typedef short bf16x8 __attribute__((ext_vector_type(8)));
typedef float f32x4 __attribute__((ext_vector_type(4)));
typedef u16 u16x4v __attribute__((ext_vector_type(4)));

__device__ __forceinline__ float b2f(u16 h){ return __uint_as_float(((unsigned)h)<<16); }
__device__ __forceinline__ u16 f2b(float f){
  unsigned u = __float_as_uint(f);
  u += 0x7fffu + ((u>>16)&1u);
  return (u16)(u>>16);
}
__device__ __forceinline__ float sigm(float x){ return 1.f/(1.f+__expf(-x)); }
__device__ __forceinline__ float tanh_(float x){
  float ax=fabsf(x), e=__expf(-2.f*ax), t=(1.f-e)/(1.f+e);
  return x<0.f? -t : t;
}
// 2x8B form: load-bearing for regalloc (16B tuple variant re-triggered spills).
__device__ __forceinline__ bf16x8 ld8a(const u16* p){
  union{ u16x4v h[2]; bf16x8 v; } u;
  u.h[0]=*(const u16x4v*)p; u.h[1]=*(const u16x4v*)(p+4); return u.v;
}
__device__ __forceinline__ f32x4 mfma16(bf16x8 a, bf16x8 b, f32x4 c){
  return __builtin_amdgcn_mfma_f32_16x16x32_bf16(a,b,c,0,0,0);
}

#define VMW(N)  do{ asm volatile("s_waitcnt vmcnt(" #N ")" ::: "memory"); \
                    __builtin_amdgcn_sched_barrier(0); }while(0)
#define LGK0    do{ asm volatile("s_waitcnt lgkmcnt(0)" ::: "memory"); \
                    __builtin_amdgcn_sched_barrier(0); }while(0)
#define BAR()   do{ asm volatile("" ::: "memory"); __builtin_amdgcn_s_barrier(); \
                    asm volatile("" ::: "memory"); __builtin_amdgcn_sched_barrier(0); }while(0)

__device__ __forceinline__ void gl_lds16(const void* g, void* s){
  __builtin_amdgcn_global_load_lds(
      (const __attribute__((address_space(1))) void*)g,
      (__attribute__((address_space(3))) void*)s, 16, 0, 0);
}
__device__ __forceinline__ void stage_rows(const u16* base, int ld, int kc,
                                           u16* buf, int w, int l){
  #pragma unroll
  for (int ii=0; ii<6; ii++){
    const int i   = w + ii*8;
    const int row = i*16 + (l>>2);
    const int c8  = (l&3) ^ ((row>>2)&3);
    gl_lds16(base + (long)row*ld + kc*32 + c8*8, buf + i*512);
  }
}
__device__ __forceinline__ bf16x8 ldB(const u16* buf, int row, int l){
  const int slot = (l>>4) ^ ((row>>2)&3);
  return *(const bf16x8*)((const char*)buf + row*64 + slot*16);
}

// ---------------------------------------------------------------------------
// K0: weight conversion. grid.y = segment.
// ---------------------------------------------------------------------------
__global__ __launch_bounds__(256) void cvt_kernel(
    const float* __restrict__ WihS, const float* __restrict__ WhhS,
    const float* __restrict__ WihC, const float* __restrict__ WhhC,
    const float* __restrict__ Wac,  const float* __restrict__ Wext,
    const float* __restrict__ Wj,
    const float* __restrict__ bihS, const float* __restrict__ bhhS,
    const float* __restrict__ bihC, const float* __restrict__ bhhC,
    u16* __restrict__ WihP, u16* __restrict__ WhhSb,
    u16* __restrict__ WihCP, u16* __restrict__ WhhCb,
    u16* __restrict__ WacB, u16* __restrict__ WextB, u16* __restrict__ WjB,
    float* __restrict__ biasGI, float* __restrict__ biasGIC)
{
  const int seg = blockIdx.y;
  int n;
  switch(seg){
    case 0: n = 768*320; break;  case 1: n = 196608; break;
    case 2: n = 768*320; break;  case 3: n = 196608; break;
    case 4: n = 65536; break;    case 5: n = 131072; break;
    case 6: n = 262144; break;   default: n = 1536; break;
  }
  for (int i = blockIdx.x*256 + threadIdx.x; i < n; i += gridDim.x*256){
    switch(seg){
      case 0: { int r=i/320, c=i-r*320; WihP[i]  = (c<300)? f2b(WihS[r*300+c]) : (u16)0; } break;
      case 1: WhhSb[i] = f2b(WhhS[i]); break;
      case 2: { int r=i/320, c=i-r*320; WihCP[i] = (c<300)? f2b(WihC[r*300+c]) : (u16)0; } break;
      case 3: WhhCb[i] = f2b(WhhC[i]); break;
      case 4: WacB[i]  = f2b(Wac[i]);  break;
      case 5: WextB[i] = f2b(Wext[i]); break;
      case 6: WjB[i]   = f2b(Wj[i]);   break;
      default:
        if (i < 768) biasGI[i] = bihS[i] + (i < 512 ? bhhS[i] : 0.f);
        else { int j = i - 768; biasGIC[j] = bihC[j] + (j < 512 ? bhhC[j] : 0.f); }
        break;
    }
  }
}

// ---------------------------------------------------------------------------
// K1: gi GEMM, 512 threads, counted-vmcnt DMA pipeline (measured best:
// non-rec remainder 297us in r13). Blocks 0..1023: sentences {2b,2b+1} x 32
// steps; block 1024 (pass 0): claim rows -> giC.
// ---------------------------------------------------------------------------
__global__ __launch_bounds__(512) void gi_kernel(
    const int pass,
    const float* __restrict__ sents, const float* __restrict__ claim,
    const u16* __restrict__ WihP, const float* __restrict__ biasGI,
    const u16* __restrict__ WihCP, const float* __restrict__ biasGIC,
    u16* __restrict__ gi_b, float* __restrict__ giC)
{
  __shared__ __align__(16) u16 SA[64*320];      // 40 KB swizzled A-tile
  __shared__ __align__(16) u16 BB[2][768*32];   // 2 x 48 KB Wih K-chunks
  const int tid=threadIdx.x, w=tid>>6, l=tid&63, ar=l&15, kg8=(l>>4)*8;
  const f32x4 z4 = {0.f,0.f,0.f,0.f};
  const bool isClaim = (blockIdx.x == 1024);
  const int b = blockIdx.x;

  for (int i=tid; i<64*80; i+=512){
    int r = i/80, q = i - r*80;
    u16x4v o;
    if (q < 75){
      float4 v;
      if (!isClaim) v = ((const float4*)sents)[(long)(2*b + (r>>5))*4800 + (pass*32 + (r&31))*75 + q];
      else          v = ((const float4*)claim)[r*75 + q];
      o[0]=f2b(v.x); o[1]=f2b(v.y); o[2]=f2b(v.z); o[3]=f2b(v.w);
    } else { o[0]=0; o[1]=0; o[2]=0; o[3]=0; }
    int byte = r*640 + q*8; byte ^= (r&7)<<4;
    *(u16x4v*)((char*)SA + byte) = o;
  }
  const u16* Bw = isClaim ? WihCP : WihP;
  stage_rows(Bw, 320, 0, BB[0], w, l);
  stage_rows(Bw, 320, 1, BB[1], w, l);
  LGK0;
  BAR();

  f32x4 acc[24];
  #pragma unroll
  for (int q=0;q<24;q++) acc[q]=z4;

  #pragma unroll
  for (int kc=0;kc<10;kc++){
    if (kc==9) VMW(0); else VMW(6);
    BAR();
    bf16x8 bq[6];
    #pragma unroll
    for (int q=0;q<6;q++) bq[q] = ldB(BB[kc&1], w*96 + q*16 + ar, l);
    #pragma unroll
    for (int m=0;m<4;m++){
      const int abyte = ((m*16+ar)*640 + (kc*32+kg8)*2) ^ ((ar&7)<<4);
      const bf16x8 a = *(const bf16x8*)((const char*)SA + abyte);
      #pragma unroll
      for (int q=0;q<6;q++) acc[m*6+q] = mfma16(a, bq[q], acc[m*6+q]);
    }
    BAR();
    if (kc<8) stage_rows(Bw, 320, kc+2, BB[kc&1], w, l);
  }
  VMW(0);
  const int rb = (l>>4)*4;
  if (!isClaim){
    #pragma unroll
    for (int q=0;q<6;q++){
      const int c = w*96 + q*16 + ar;
      const float bs = biasGI[c];
      #pragma unroll
      for (int m=0;m<4;m++)
        #pragma unroll
        for (int p=0;p<4;p++)
          gi_b[(long)(b*64 + m*16 + rb + p)*768 + c] = f2b(acc[m*6+q][p] + bs);
    }
  } else {
    #pragma unroll
    for (int q=0;q<6;q++){
      const int c = w*96 + q*16 + ar;
      const float bs = biasGIC[c];
      #pragma unroll
      for (int m=0;m<4;m++)
        #pragma unroll
        for (int p=0;p<4;p++)
          giC[(m*16 + rb + p)*768 + c] = acc[m*6+q][p] + bs;
    }
  }
}

// ---------------------------------------------------------------------------
// K2: recurrence — VERBATIM the round-10/16-measured best (232 us/pass):
// wf[6][8] nominally register-resident (RA caps at 128 and spills ~64; that
// spilled configuration is empirically the fastest of 13 rec variants),
// giL rows padded to 776, claim GRU at block 0, 8 sentences/block x 256.
// ---------------------------------------------------------------------------
__global__ __launch_bounds__(512) void rec_kernel(
    const int pass,
    const u16* __restrict__ gi_b, const u16* __restrict__ WhhSb,
    const float* __restrict__ bhhS,
    float* __restrict__ Hmid, u16* __restrict__ HSout,
    const float* __restrict__ giC, const u16* __restrict__ WhhCb,
    const float* __restrict__ bhhC, const float* __restrict__ Wj,
    const float* __restrict__ WgC,
    float* __restrict__ hcMid, float* __restrict__ hcf,
    float* __restrict__ cvec, float* __restrict__ c0p)
{
  __shared__ __align__(16) u16 Hb[2][16][256];
  __shared__ __align__(16) u16 giL[2][8][776];
  __shared__ float ghL[768];
  __shared__ float hfL[256];
  __shared__ __align__(16) u16 hbL[256];
  const int tid=threadIdx.x, w=tid>>6, l=tid&63, ar=l&15, kg8=(l>>4)*8;
  const f32x4 z4 = {0.f,0.f,0.f,0.f};
  asm volatile("" ::: "v250");

  if (blockIdx.x != 0){
    const long i0 = (long)(blockIdx.x - 1)*8;
    const int rb = (l>>4)*4;
    bf16x8 wf[6][8];
    #pragma unroll
    for (int s=0;s<3;s++)
      #pragma unroll
      for (int ti=0;ti<2;ti++)
        #pragma unroll
        for (int kc=0;kc<8;kc++)
          wf[s*2+ti][kc] = ld8a(WhhSb + (s*256 + w*32 + ti*16 + ar)*256 + kc*32 + kg8);
    const float bhn0 = bhhS[512 + w*32 +  0 + ar];
    const float bhn1 = bhhS[512 + w*32 + 16 + ar];

    for (int i=tid; i<2*16*256; i+=512) ((u16*)Hb)[i] = 0;
    __syncthreads();
    float hold[2][4];
    #pragma unroll
    for (int ti=0;ti<2;ti++)
      #pragma unroll
      for (int p=0;p<4;p++) hold[ti][p] = 0.f;
    if (pass==1 && l<32){
      #pragma unroll
      for (int ti=0;ti<2;ti++){
        #pragma unroll
        for (int p=0;p<4;p++){
          const int c = w*32 + ti*16 + ar, rr = rb + p;
          const float h = Hmid[(i0+rr)*256 + c];
          hold[ti][p] = h;
          const int byte = (rr*512 + c*2) ^ ((rr&7)<<4);
          *(u16*)((char*)&Hb[0][0][0] + byte) = f2b(h);
        }
      }
    }
    const u32* g32 = (const u32*)gi_b;
    u32 pf[6];
    #pragma unroll
    for (int rep=0;rep<6;rep++){
      const int i = rep*512 + tid, j = i/384, cu = i - j*384;
      pf[rep] = g32[((i0+j)*32 + 0)*384 + cu];
    }
    #pragma unroll
    for (int rep=0;rep<6;rep++){
      const int i = rep*512 + tid, j = i/384, cu = i - j*384;
      *(u32*)((char*)&giL[0][0][0] + j*1552 + cu*4) = pf[rep];
    }
    __syncthreads();

    int cur = 0;
    for (int tl=0; tl<32; tl++){
      const int tn = (tl<31) ? tl+1 : 31;
      #pragma unroll
      for (int rep=0;rep<6;rep++){
        const int i = rep*512 + tid, j = i/384, cu = i - j*384;
        pf[rep] = g32[((i0+j)*32 + tn)*384 + cu];
      }
      f32x4 acc[6];
      #pragma unroll
      for (int q=0;q<6;q++) acc[q]=z4;
      if (l < 32){
        #pragma unroll
        for (int s=0;s<2;s++)
          #pragma unroll
          for (int ti=0;ti<2;ti++)
            #pragma unroll
            for (int p=0;p<4;p++){
              const int c = w*32 + ti*16 + ar;
              const u16 v = *(const u16*)((const char*)&giL[cur][0][0] + (rb+p)*1552 + (s*256+c)*2);
              acc[s*2+ti][p] = b2f(v);
            }
      }
      #pragma unroll
      for (int kc=0;kc<8;kc++){
        const int abyte = (ar*512 + (kc*32+kg8)*2) ^ ((ar&7)<<4);
        const bf16x8 a = *(const bf16x8*)((const char*)&Hb[cur][0][0] + abyte);
        #pragma unroll
        for (int q=0;q<6;q++) acc[q] = mfma16(a, wf[q][kc], acc[q]);
      }
      #pragma unroll
      for (int rep=0;rep<6;rep++){
        const int i = rep*512 + tid, j = i/384, cu = i - j*384;
        *(u32*)((char*)&giL[cur^1][0][0] + j*1552 + cu*4) = pf[rep];
      }
      if (l < 32){
        #pragma unroll
        for (int ti=0;ti<2;ti++){
          const int c = w*32 + ti*16 + ar;
          const float bhn = ti ? bhn1 : bhn0;
          #pragma unroll
          for (int p=0;p<4;p++){
            const int rr = rb + p;
            const u16 gv = *(const u16*)((const char*)&giL[cur][0][0] + rr*1552 + (512+c)*2);
            const float r_ = sigm(acc[0+ti][p]);
            const float z_ = sigm(acc[2+ti][p]);
            const float n_ = tanh_(b2f(gv) + r_*(acc[4+ti][p] + bhn));
            const float h = (1.f - z_)*n_ + z_*hold[ti][p];
            hold[ti][p] = h;
            const int byte = (rr*512 + c*2) ^ ((rr&7)<<4);
            *(u16*)((char*)&Hb[cur^1][0][0] + byte) = f2b(h);
          }
        }
      }
      __syncthreads();
      cur ^= 1;
    }
    if (l < 32){
      #pragma unroll
      for (int ti=0;ti<2;ti++){
        #pragma unroll
        for (int p=0;p<4;p++){
          const int c = w*32 + ti*16 + ar, rr = rb + p;
          if (pass==0) Hmid[(i0+rr)*256 + c] = hold[ti][p];
          else         HSout[(i0+rr)*512 + c] = f2b(hold[ti][p]);
        }
      }
    }
  } else {
    const u16* wrow[6];
    #pragma unroll
    for (int q=0;q<6;q++) wrow[q] = WhhCb + (w*96 + q*16 + ar)*256 + kg8;
    if (tid < 256){
      const float h0 = (pass==0) ? 0.f : hcMid[tid];
      hfL[tid] = h0; hbL[tid] = f2b(h0);
    }
    __syncthreads();
    for (int tl=0; tl<32; tl++){
      const int t = pass*32 + tl;
      f32x4 a6[6];
      #pragma unroll
      for (int q=0;q<6;q++) a6[q]=z4;
      #pragma unroll
      for (int kc=0;kc<8;kc++){
        bf16x8 wq[6];
        #pragma unroll
        for (int q=0;q<6;q++) wq[q] = ld8a(wrow[q] + kc*32);
        const bf16x8 a = ld8a((const u16*)hbL + kc*32 + kg8);
        #pragma unroll
        for (int q=0;q<6;q++) a6[q] = mfma16(a, wq[q], a6[q]);
      }
      if (l < 16){
        #pragma unroll
        for (int q=0;q<6;q++) ghL[w*96 + q*16 + l] = a6[q][0];
      }
      __syncthreads();
      if (tid < 256){
        const int c = tid;
        const float r_ = sigm(giC[t*768 +       c] + ghL[c]);
        const float z_ = sigm(giC[t*768 + 256 + c] + ghL[256 + c]);
        const float n_ = tanh_(giC[t*768 + 512 + c] + r_*(ghL[512 + c] + bhhC[512 + c]));
        const float h = (1.f - z_)*n_ + z_*hfL[c];
        hfL[c] = h; hbL[c] = f2b(h);
      }
      __syncthreads();
    }
    if (tid < 256){
      const int c = tid;
      const float hv = hfL[c];
      if (pass == 0) hcMid[c] = hv;
      else {
        hcf[c] = hv;
        float acc2 = 0.f;
        for (int k=0;k<256;k++) acc2 += hfL[k]*Wj[(long)c*1024 + k];
        cvec[c] = acc2;
        if (c==0){ float s=0.f; for (int k=0;k<256;k++) s += hfL[k]*WgC[k]; *c0p = s; }
      }
    }
  }
}

// ---------------------------------------------------------------------------
// K3: gated fusion -> HSg (row-major) and HSgT (transposed)
// ---------------------------------------------------------------------------
__global__ __launch_bounds__(256) void fusion_kernel(
    const u16* __restrict__ HSH, const float* __restrict__ Wgs,
    const float* __restrict__ hcf, const float* __restrict__ c0p,
    u16* __restrict__ HSg, u16* __restrict__ HSgT)
{
  __shared__ float gbuf[64];
  __shared__ __align__(16) u16 tile[64][258];
  const int tid=threadIdx.x, w=tid>>6, l=tid&63;
  const long i0 = (long)blockIdx.x * 64;
  const float c0 = *c0p;
  for (int rr=0; rr<16; rr++){
    long i = i0 + w*16 + rr;
    float p = 0.f;
    for (int c=l; c<256; c+=64) p += b2f(HSH[i*512+c]) * Wgs[c];
    for (int o=32;o;o>>=1) p += __shfl_down(p,o,64);
    if (l==0) gbuf[w*16+rr] = sigm(p + c0);
  }
  __syncthreads();
  for (int idx=tid; idx<64*256; idx+=256){
    int r = idx>>8, c = idx&255;
    float g = gbuf[r];
    float hs = b2f(HSH[(i0+r)*512 + c]);
    u16 bv = f2b(g*hs + (1.f-g)*hcf[c]);
    HSg[(i0+r)*256 + c] = bv;
    tile[r][c] = bv;
  }
  __syncthreads();
  const int ioff = tid&63, cg = tid>>6;
  for (int cc=cg; cc<256; cc+=4)
    HSgT[(long)cc*2048 + i0 + ioff] = tile[ioff][cc];
}

// ---------------------------------------------------------------------------
// Generic MFMA GEMM: C[M,N] = A[M,K] @ Bw[N,K]^T. 64x64 per block.
// ---------------------------------------------------------------------------
template<int MODE>
__global__ __launch_bounds__(256) void gemmk(
    const u16* __restrict__ A, long lda,
    const u16* __restrict__ Bw, long ldb,
    void* __restrict__ Cp, long ldc, int K,
    const float* __restrict__ biasf,
    const float* __restrict__ hc)
{
  const int tid=threadIdx.x, w=tid>>6, l=tid&63, ar=l&15, kg8=(l>>4)*8;
  const long row0 = (long)blockIdx.x*64 + w*16;
  const long col0 = (long)blockIdx.y*64;
  const f32x4 z4 = {0.f,0.f,0.f,0.f};
  f32x4 acc[4] = {z4,z4,z4,z4};
  const u16* ap = A + (row0+ar)*lda + kg8;
  const u16* bp0 = Bw + (col0+ 0+ar)*ldb + kg8;
  const u16* bp1 = Bw + (col0+16+ar)*ldb + kg8;
  const u16* bp2 = Bw + (col0+32+ar)*ldb + kg8;
  const u16* bp3 = Bw + (col0+48+ar)*ldb + kg8;
  for (int k0=0; k0<K; k0+=32){
    bf16x8 a = ld8a(ap + k0);
    acc[0] = mfma16(a, ld8a(bp0+k0), acc[0]);
    acc[1] = mfma16(a, ld8a(bp1+k0), acc[1]);
    acc[2] = mfma16(a, ld8a(bp2+k0), acc[2]);
    acc[3] = mfma16(a, ld8a(bp3+k0), acc[3]);
  }
  const int rbase = (l>>4)*4;
  #pragma unroll
  for (int t=0;t<4;t++){
    long c = col0 + t*16 + ar;
    #pragma unroll
    for (int p=0;p<4;p++){
      long r = row0 + rbase + p;
      float v = acc[t][p];
      if constexpr (MODE==0){
        if (biasf) v += biasf[c];
        ((u16*)Cp)[r*ldc + c] = f2b(v);
      } else if constexpr (MODE==1){
        ((float*)Cp)[r*ldc + c] = v;
      } else if constexpr (MODE==2){
        float tv = tanh_(v + biasf[c]);
        u16* Uo = (u16*)Cp;
        float hv = hc[c];
        Uo[r*768 + c]       = f2b(tv);
        Uo[r*768 + 256 + c] = f2b(hv*tv);
        Uo[r*768 + 512 + c] = f2b(fabsf(hv - tv));
      } else {
        float tv = tanh_(v + biasf[c]);
        ((u16*)Cp)[r*ldc + c] = f2b(tv);
      }
    }
  }
}

// ---------------------------------------------------------------------------
// K5: row softmax on S (f32, ld 2048) -> bf16 P in place (ld 4096 u16)
// ---------------------------------------------------------------------------
__global__ __launch_bounds__(256) void softmax_rows(float* __restrict__ S)
{
  __shared__ float buf[2048];
  __shared__ float red[4];
  const long i = blockIdx.x;
  float* row = S + i*2048;
  const int tid = threadIdx.x;
  float m = -1e30f;
  for (int c=tid; c<2048; c+=256){ float v=row[c]; buf[c]=v; m=fmaxf(m,v); }
  for (int o=32;o;o>>=1) m = fmaxf(m, __shfl_down(m,o,64));
  if ((tid&63)==0) red[tid>>6] = m;
  __syncthreads();
  m = fmaxf(fmaxf(red[0],red[1]), fmaxf(red[2],red[3]));
  __syncthreads();
  float s = 0.f;
  for (int c=tid; c<2048; c+=256){ float e=__expf(buf[c]-m); buf[c]=e; s+=e; }
  for (int o=32;o;o>>=1) s += __shfl_down(s,o,64);
  if ((tid&63)==0) red[tid>>6] = s;
  __syncthreads();
  s = red[0]+red[1]+red[2]+red[3];
  const float rinv = 1.f/s;
  u16* P = (u16*)S + i*4096;
  for (int c=tid; c<2048; c+=256) P[c] = f2b(buf[c]*rinv);
}

// ---------------------------------------------------------------------------
// K9: entailment attention partials
// ---------------------------------------------------------------------------
__global__ __launch_bounds__(256) void ae_kernel(
    const u16* __restrict__ Hcs, const float* __restrict__ Wae, const float* __restrict__ bae,
    float* __restrict__ part, float* __restrict__ psum)
{
  __shared__ float aebuf[64];
  const int b=blockIdx.x, tid=threadIdx.x, w=tid>>6, l=tid&63;
  const long i0 = (long)b*64;
  const float baev = bae[0];
  for (int rr=0; rr<16; rr++){
    long i = i0 + w*16 + rr;
    float p = 0.f;
    for (int c=l; c<256; c+=64) p += b2f(Hcs[i*256+c]) * Wae[c];
    for (int o=32;o;o>>=1) p += __shfl_down(p,o,64);
    if (l==0) aebuf[w*16+rr] = __expf(tanh_(p + baev));
  }
  __syncthreads();
  float acc = 0.f;
  const int c = tid;
  for (int r=0;r<64;r++) acc += aebuf[r] * b2f(Hcs[(i0+r)*256 + c]);
  part[b*256 + c] = acc;
  if (tid==0){ float s=0.f; for (int r=0;r<64;r++) s+=aebuf[r]; psum[b]=s; }
}

__global__ __launch_bounds__(256) void final_kernel(
    const float* __restrict__ part, const float* __restrict__ psum,
    const float* __restrict__ Wf, const float* __restrict__ bf_, float* __restrict__ out)
{
  __shared__ float hbuf[256];
  __shared__ float ssum;
  const int tid = threadIdx.x;
  float v = 0.f;
  for (int b=0;b<32;b++) v += part[b*256 + tid];
  hbuf[tid] = v;
  if (tid==0){ float s=0.f; for (int b=0;b<32;b++) s+=psum[b]; ssum=s; }
  __syncthreads();
  const int w = tid>>6, l = tid&63;
  if (w < 2){
    float rinv = 1.f/ssum;
    float p = 0.f;
    for (int c=l; c<256; c+=64) p += hbuf[c]*rinv*Wf[w*256 + c];
    for (int o=32;o;o>>=1) p += __shfl_down(p,o,64);
    if (l==0) out[w] = sigm(p + bf_[w]);
  }
}

extern "C" void kernel_launch(void* const* d_in, const int* in_sizes, int n_in,
                              void* d_out, int out_size, void* d_ws, size_t ws_size,
                              hipStream_t stream)
{
  const float* claim=(const float*)d_in[0];
  const float* sents=(const float*)d_in[1];
  const float* WihC =(const float*)d_in[2];
  const float* WhhC =(const float*)d_in[3];
  const float* bihC =(const float*)d_in[4];
  const float* bhhC =(const float*)d_in[5];
  const float* WihS =(const float*)d_in[6];
  const float* WhhS =(const float*)d_in[7];
  const float* bihS =(const float*)d_in[8];
  const float* bhhS =(const float*)d_in[9];
  const float* WgS  =(const float*)d_in[10];
  const float* WgC  =(const float*)d_in[11];
  const float* Wac  =(const float*)d_in[12];
  const float* bac  =(const float*)d_in[13];
  // d_in[14] Was, d_in[15] bas: row-constant in scores -> softmax-invariant
  const float* Wext =(const float*)d_in[16];
  const float* bext =(const float*)d_in[17];
  const float* Wj   =(const float*)d_in[18];
  const float* Wae  =(const float*)d_in[19];
  const float* bae  =(const float*)d_in[20];
  const float* Wf   =(const float*)d_in[21];
  const float* bf_  =(const float*)d_in[22];

  char* ws = (char*)d_ws;
  size_t off = 0;
  auto alloc = [&](size_t b)->void*{ void* p = ws + off; off = (off + b + 255) & ~(size_t)255; return p; };
  float* hcf  = (float*)alloc(256*4);
  float* cvec = (float*)alloc(256*4);
  float* c0p  = (float*)alloc(16);
  float* hcMid= (float*)alloc(256*4);
  float* giC  = (float*)alloc((size_t)64*768*4);
  u16* WihP   = (u16*)alloc((size_t)768*320*2);
  u16* WhhSb  = (u16*)alloc((size_t)196608*2);
  u16* WihCP  = (u16*)alloc((size_t)768*320*2);
  u16* WhhCb  = (u16*)alloc((size_t)196608*2);
  u16* WacB   = (u16*)alloc((size_t)65536*2);
  u16* WextB  = (u16*)alloc((size_t)131072*2);
  u16* WjB    = (u16*)alloc((size_t)262144*2);
  float* biasGI  = (float*)alloc(768*4);
  float* biasGIC = (float*)alloc(768*4);
  u16* HSH  = (u16*)alloc((size_t)2048*512*2);   // [HS | H_apo]
  u16* HSg  = (u16*)alloc((size_t)2048*256*2);
  u16* HSgT = (u16*)alloc((size_t)256*2048*2);
  u16* A1   = (u16*)alloc((size_t)2048*256*2);
  u16* Up   = (u16*)alloc((size_t)2048*768*2);   // [Ht | hc*Ht | |hc-Ht|]
  u16* Hcs  = (u16*)alloc((size_t)2048*256*2);
  float* part = (float*)alloc(32*256*4);
  float* psum = (float*)alloc(32*4);
  float* Hmid = (float*)alloc((size_t)2048*256*4);
  u16* gi_b   = (u16*)alloc((size_t)65536*768*2);  // 100.7 MB, per-pass
  float* S    = (float*)gi_b;                       // aliased (gi dead when S live)

  cvt_kernel<<<dim3(960,8),256,0,stream>>>(WihS,WhhS,WihC,WhhC,Wac,Wext,Wj,
                                           bihS,bhhS,bihC,bhhC,
                                           WihP,WhhSb,WihCP,WhhCb,WacB,WextB,WjB,
                                           biasGI,biasGIC);
  // pass 0 (t 0..31) + claim gi (block 1024)
  gi_kernel<<<1025,512,0,stream>>>(0,sents,claim,WihP,biasGI,WihCP,biasGIC,gi_b,giC);
  rec_kernel<<<257,512,0,stream>>>(0,gi_b,WhhSb,bhhS,Hmid,HSH,
                                   giC,WhhCb,bhhC,Wj,WgC,hcMid,hcf,cvec,c0p);
  // pass 1 (t 32..63)
  gi_kernel<<<1024,512,0,stream>>>(1,sents,claim,WihP,biasGI,WihCP,biasGIC,gi_b,giC);
  rec_kernel<<<257,512,0,stream>>>(1,gi_b,WhhSb,bhhS,Hmid,HSH,
                                   giC,WhhCb,bhhC,Wj,WgC,hcMid,hcf,cvec,c0p);

  fusion_kernel<<<32,256,0,stream>>>(HSH,WgS,hcf,c0p,HSg,HSgT);
  gemmk<0><<<dim3(32,4),256,0,stream>>>(HSg,256L,WacB,256L,(void*)A1,256L,256,bac,nullptr);
  gemmk<1><<<dim3(32,32),256,0,stream>>>(A1,256L,HSg,256L,(void*)S,2048L,256,nullptr,nullptr);
  softmax_rows<<<2048,256,0,stream>>>(S);
  gemmk<0><<<dim3(32,4),256,0,stream>>>((const u16*)S,4096L,HSgT,2048L,(void*)(HSH+256),512L,2048,nullptr,nullptr);
  gemmk<2><<<dim3(32,4),256,0,stream>>>(HSH,512L,WextB,512L,(void*)Up,768L,512,bext,hcf);
  gemmk<3><<<dim3(32,4),256,0,stream>>>(Up,768L,WjB+256,1024L,(void*)Hcs,256L,768,cvec,nullptr);
  ae_kernel<<<32,256,0,stream>>>(Hcs,Wae,bae,part,psum);
  final_kernel<<<1,256,0,stream>>>(part,psum,Wf,bf_,(float*)d_out);
}